// Round 18
// baseline (63.206 us; speedup 1.0000x reference)
//
#include <hip/hip_runtime.h>

#define N 8192

// Binned autocorrelation for the smooth part: H8 (8 non-min images) + g_cap(r_min),
// where g_cap(r) = 1/r for r >= rc and the C1-matched poly below rc.
#define BGRID 64
#define BINV 6.4f                  // 1/h, h = 10/64
#define NBINS (BGRID * BGRID)      // 4096
#define FDIM 127                   // signed bin offsets -63..63
#define FSIZE (FDIM * FDIM)        // 16129
#define FH 0.15625f                // 10/64

// poly(s) = GA + GB*s + GC*s^2 (s = r^2), C1-matched to 1/r at rc=0.5.
#define RC2 0.25f
#define GA 3.75f
#define GB (-10.0f)
#define GC 12.0f

// Cell list for the short-range residual (1/r - poly, nonzero only r < 0.5).
#define CELLG 20
#define CELLINV 2.0f
#define NCELLS (CELLG * CELLG)     // 400

#define FBLOCKS 64
#define HISTBLOCKS 4
#define KEBLOCKS 8
#define NCORR 512
#define SRBLOCKS 64                // 64 x 128 threads = 8192 points

// ws layout (float-index offsets)
#define WS_F 0                     // 16384
#define WS_HIST 16384              // 4*4096 u32
#define WS_SORT 32768              // 8192 float2
#define WS_CSTART 49152            // 401 ints (pad 512)
#define WS_CORR 49664              // 512
#define WS_SR 50176                // 64
#define WS_KE 50240                // 8

#define RSQ __builtin_amdgcn_rsqf

// prep roles: [0,64) F table; [64,68) hist; [68,76) KE; 76 cell-list build.
__global__ __launch_bounds__(256) void prep_kernel(const float* __restrict__ xy,
                                                   const float* __restrict__ pxy,
                                                   float* __restrict__ F,
                                                   unsigned* __restrict__ hist,
                                                   float* __restrict__ ke_part,
                                                   float2* __restrict__ sorted,
                                                   int* __restrict__ cell_start) {
    const int t = threadIdx.x;
    const int b = blockIdx.x;
    if (b < FBLOCKS) {
        int k = b * 256 + t;
        if (k < FSIZE) {
            float a  = (float)(k % FDIM - 63) * FH;
            float bb = (float)(k / FDIM - 63) * FH;
            // 8 non-min images exactly
            int ixm = (__builtin_fabsf(a)  <= 5.0f) ? 0 : (a  > 0.0f ? -1 : 1);
            int iym = (__builtin_fabsf(bb) <= 5.0f) ? 0 : (bb > 0.0f ? -1 : 1);
            float s = 0.0f;
            for (int iy = -1; iy <= 1; ++iy)
                for (int ix = -1; ix <= 1; ++ix) {
                    if (ix == ixm && iy == iym) continue;
                    float xs = __builtin_fmaf(10.0f, (float)ix, a);
                    float ys = __builtin_fmaf(10.0f, (float)iy, bb);
                    s += RSQ(xs * xs + ys * ys);
                }
            // + g_cap(r_min): 1/r beyond rc, C1-matched poly below (THE R17 BUG:
            // poly was applied unconditionally; it diverges as s^2 for r >> rc).
            float ux = 5.0f - __builtin_fabsf(__builtin_fabsf(a) - 5.0f);
            float uy = 5.0f - __builtin_fabsf(__builtin_fabsf(bb) - 5.0f);
            float r2 = __builtin_fmaf(uy, uy, ux * ux);
            float gcap = (r2 >= RC2)
                       ? RSQ(r2)
                       : __builtin_fmaf(__builtin_fmaf(GC, r2, GB), r2, GA);
            F[k] = s + gcap;
        }
    } else if (b < FBLOCKS + HISTBLOCKS) {
        __shared__ unsigned lh[NBINS];
        const int hb = b - FBLOCKS;
        for (int k = t; k < NBINS; k += 256) lh[k] = 0u;
        __syncthreads();
        const float2* p2 = (const float2*)xy;
        for (int r = 0; r < 8; ++r) {
            float2 p = p2[hb * 2048 + r * 256 + t];
            int cx = (int)(p.x * BINV); cx = cx > 63 ? 63 : cx;
            int cy = (int)(p.y * BINV); cy = cy > 63 ? 63 : cy;
            atomicAdd(&lh[cy * BGRID + cx], 1u);
        }
        __syncthreads();
        for (int k = t; k < NBINS; k += 256) hist[hb * NBINS + k] = lh[k];
    } else if (b < FBLOCKS + HISTBLOCKS + KEBLOCKS) {
        const int kb = b - FBLOCKS - HISTBLOCKS;
        const float4* p4 = (const float4*)pxy;
        float acc = 0.0f;
        for (int k = kb * 256 + t; k < (2 * N) / 4; k += KEBLOCKS * 256) {
            float4 v = p4[k];
            acc += 0.5f * (v.x * v.x + v.y * v.y + v.z * v.z + v.w * v.w);
        }
        for (int off = 32; off > 0; off >>= 1)
            acc += __shfl_down(acc, off, 64);
        __shared__ float ws[4];
        if ((t & 63) == 0) ws[t >> 6] = acc;
        __syncthreads();
        if (t == 0) ke_part[kb] = (ws[0] + ws[1]) + (ws[2] + ws[3]);
    } else {
        // ---- cell-list build (single block) ----
        __shared__ unsigned cnt[NCELLS];   // counts -> exclusive starts -> run offsets
        const float2* p2 = (const float2*)xy;
        for (int k = t; k < NCELLS; k += 256) cnt[k] = 0u;
        __syncthreads();
        for (int k = t; k < N; k += 256) {
            float2 p = p2[k];
            int cx = (int)(p.x * CELLINV); cx = cx > CELLG - 1 ? CELLG - 1 : cx;
            int cy = (int)(p.y * CELLINV); cy = cy > CELLG - 1 ? CELLG - 1 : cy;
            atomicAdd(&cnt[cy * CELLG + cx], 1u);
        }
        __syncthreads();
        // exclusive prefix scan over 400 entries: one wave64, 7 chunks
        if (t < 64) {
            unsigned carry = 0u;
            for (int ch = 0; ch < 7; ++ch) {
                int idx = ch * 64 + t;
                unsigned v = (idx < NCELLS) ? cnt[idx] : 0u;
                unsigned x = v;
                for (int off = 1; off < 64; off <<= 1) {
                    unsigned y = __shfl_up(x, off, 64);
                    if (t >= off) x += y;
                }
                unsigned excl = carry + x - v;
                if (idx < NCELLS) {
                    cell_start[idx] = (int)excl;
                    cnt[idx] = excl;           // running offset for pass 2
                }
                carry += __shfl(x, 63, 64);
            }
            if (t == 0) cell_start[NCELLS] = (int)carry;   // == N
        }
        __syncthreads();
        for (int k = t; k < N; k += 256) {
            float2 p = p2[k];
            int cx = (int)(p.x * CELLINV); cx = cx > CELLG - 1 ? CELLG - 1 : cx;
            int cy = (int)(p.y * CELLINV); cy = cy > CELLG - 1 ? CELLG - 1 : cy;
            unsigned slot = atomicAdd(&cnt[cy * CELLG + cx], 1u);
            sorted[slot] = p;
        }
    }
}

// main: [0,512) binned autocorr of F; [512,576) short-range residual via cells.
__global__ __launch_bounds__(128) void main_kernel(const float* __restrict__ F,
                                                   const unsigned* __restrict__ hist,
                                                   const float2* __restrict__ sorted,
                                                   const int* __restrict__ cell_start,
                                                   float* __restrict__ corr_part,
                                                   float* __restrict__ sr_part) {
    const int t = threadIdx.x;
    __shared__ float wsum[2];

    if (blockIdx.x < NCORR) {
        __shared__ float corrF[8][128];
        __shared__ float corrN[8][64];
        const int cid = blockIdx.x;
        const int y1 = cid >> 3;
        const int y2b = (cid & 7) * 8;
        const int x1 = t & 63;
        const int x2c = t >> 6;
        const int x2base = x2c * 32;
#pragma unroll
        for (int s = 0; s < 8; ++s) {
            if (t < FDIM)
                corrF[s][t] = F[(y1 - (y2b + s) + 63) * FDIM + t];
            if (t < 64) {
                int hi = (y2b + s) * BGRID + t;
                corrN[s][t] = (float)(hist[hi] + hist[NBINS + hi]
                                    + hist[2 * NBINS + hi] + hist[3 * NBINS + hi]);
            }
        }
        int h1 = y1 * BGRID + x1;
        float n1 = (float)(hist[h1] + hist[NBINS + h1]
                         + hist[2 * NBINS + h1] + hist[3 * NBINS + h1]);
        __syncthreads();
        const int fb = 63 + x1 - x2base;
        float acc = 0.0f;
#pragma unroll
        for (int s = 0; s < 8; ++s) {
            const float* Fr = &corrF[s][0];
            const float* Nr = &corrN[s][x2base];
            float sum = 0.0f;
#pragma unroll 8
            for (int k = 0; k < 32; ++k)
                sum = __builtin_fmaf(Nr[k], Fr[fb - k], sum);
            acc += sum;
        }
        acc *= n1;
        for (int off = 32; off > 0; off >>= 1)
            acc += __shfl_down(acc, off, 64);
        if ((t & 63) == 0) wsum[t >> 6] = acc;
        __syncthreads();
        if (t == 0) corr_part[cid] = wsum[0] + wsum[1];
        return;
    }

    // ---- short-range: sum over pairs with r_min < rc of (1/r - poly) ----
    __shared__ int cs[NCELLS + 1];
    for (int k = t; k < NCELLS + 1; k += 128) cs[k] = cell_start[k];
    __syncthreads();

    const int me = (blockIdx.x - NCORR) * 128 + t;
    const float2 p = sorted[me];
    int cx = (int)(p.x * CELLINV); cx = cx > CELLG - 1 ? CELLG - 1 : cx;
    int cy = (int)(p.y * CELLINV); cy = cy > CELLG - 1 ? CELLG - 1 : cy;

    float acc = 0.0f;
    for (int dyc = -1; dyc <= 1; ++dyc) {
        int cy2 = cy + dyc;
        cy2 += (cy2 < 0) ? CELLG : 0;
        cy2 -= (cy2 >= CELLG) ? CELLG : 0;
        for (int dxc = -1; dxc <= 1; ++dxc) {
            int cx2 = cx + dxc;
            cx2 += (cx2 < 0) ? CELLG : 0;
            cx2 -= (cx2 >= CELLG) ? CELLG : 0;
            const int c = cy2 * CELLG + cx2;
            const int e = cs[c + 1];
            for (int k = cs[c]; k < e; ++k) {
                if (k == me) continue;
                float2 q = sorted[k];
                float dx = p.x - q.x;
                float dy = p.y - q.y;
                float ux = 5.0f - __builtin_fabsf(__builtin_fabsf(dx) - 5.0f);
                float uy = 5.0f - __builtin_fabsf(__builtin_fabsf(dy) - 5.0f);
                float s = __builtin_fmaf(uy, uy, ux * ux);
                float v = RSQ(s) - __builtin_fmaf(__builtin_fmaf(GC, s, GB), s, GA);
                acc += (s < RC2) ? v : 0.0f;
            }
        }
    }
    for (int off = 32; off > 0; off >>= 1)
        acc += __shfl_down(acc, off, 64);
    if ((t & 63) == 0) wsum[t >> 6] = acc;
    __syncthreads();
    if (t == 0) sr_part[blockIdx.x - NCORR] = wsum[0] + wsum[1];
}

// finish: corr + sr + KE - N*F(0) -> scalar.
__global__ __launch_bounds__(1024) void finish_kernel(const float* __restrict__ corr_part,
                                                      const float* __restrict__ sr_part,
                                                      const float* __restrict__ ke_part,
                                                      const float* __restrict__ F,
                                                      float* __restrict__ out) {
    const int t = threadIdx.x;
    float acc = 0.0f;
    if (t < NCORR) acc += corr_part[t];
    if (t < SRBLOCKS) acc += sr_part[t];
    if (t < KEBLOCKS) acc += ke_part[t];
    if (t == 0) acc -= (float)N * F[63 * FDIM + 63];   // remove i==j bin pairs
    for (int off = 32; off > 0; off >>= 1)
        acc += __shfl_down(acc, off, 64);
    __shared__ float ws[16];
    if ((t & 63) == 0) ws[t >> 6] = acc;
    __syncthreads();
    if (t == 0) {
        float s = 0.0f;
        for (int w = 0; w < 16; ++w) s += ws[w];
        out[0] = s;
    }
}

extern "C" void kernel_launch(void* const* d_in, const int* in_sizes, int n_in,
                              void* d_out, int out_size, void* d_ws, size_t ws_size,
                              hipStream_t stream) {
    const float* xy  = (const float*)d_in[0];
    const float* pxy = (const float*)d_in[1];
    float* out       = (float*)d_out;
    float* wsf       = (float*)d_ws;
    float* F         = wsf + WS_F;
    unsigned* hist   = (unsigned*)(wsf + WS_HIST);
    float2* sorted   = (float2*)(wsf + WS_SORT);
    int* cell_start  = (int*)(wsf + WS_CSTART);
    float* corr_part = wsf + WS_CORR;
    float* sr_part   = wsf + WS_SR;
    float* ke_part   = wsf + WS_KE;

    prep_kernel<<<FBLOCKS + HISTBLOCKS + KEBLOCKS + 1, 256, 0, stream>>>(
        xy, pxy, F, hist, ke_part, sorted, cell_start);
    main_kernel<<<NCORR + SRBLOCKS, 128, 0, stream>>>(
        F, hist, sorted, cell_start, corr_part, sr_part);
    finish_kernel<<<1, 1024, 0, stream>>>(corr_part, sr_part, ke_part, F, out);
}

// Round 19
// 37.985 us; speedup vs baseline: 1.6640x; 1.6640x over previous
//
#include <hip/hip_runtime.h>

#define N 8192

// Binned autocorrelation for the smooth part: H8 (8 non-min images) + g_cap(r_min),
// where g_cap(r) = 1/r for r >= rc and the C1-matched poly below rc.
#define BGRID 64
#define BINV 6.4f                  // 1/h, h = 10/64
#define NBINS (BGRID * BGRID)      // 4096
#define FDIM 127                   // signed bin offsets -63..63
#define FSIZE (FDIM * FDIM)        // 16129
#define FH 0.15625f                // 10/64

// poly(s) = GA + GB*s + GC*s^2 (s = r^2), C1-matched to 1/r at rc=0.5.
#define RC2 0.25f
#define GA 3.75f
#define GB (-10.0f)
#define GC 12.0f

// Cell list for the short-range residual (1/r - poly, nonzero only r < 0.5).
#define CELLG 20
#define CELLINV 2.0f
#define NCELLS (CELLG * CELLG)     // 400

#define FBLOCKS 64
#define HISTBLOCKS 4
#define KEBLOCKS 8
#define NCORR 512
#define SRCAP 384                  // neighborhood capacity (avg 185, +14 sigma safe)

// ws layout (float-index offsets)
#define WS_F 0                     // 16384
#define WS_HIST 16384              // 4*4096 u32
#define WS_SORT 32768              // 8192 float2
#define WS_CSTART 49152            // 401 ints (pad 512)
#define WS_CORR 49664              // 512
#define WS_SR 50176                // 400 (pad 512)
#define WS_KE 50688                // 8

#define RSQ __builtin_amdgcn_rsqf

// prep roles: [0,64) F table; [64,68) hist; [68,76) KE; 76 cell-list build.
__global__ __launch_bounds__(256) void prep_kernel(const float* __restrict__ xy,
                                                   const float* __restrict__ pxy,
                                                   float* __restrict__ F,
                                                   unsigned* __restrict__ hist,
                                                   float* __restrict__ ke_part,
                                                   float2* __restrict__ sorted,
                                                   int* __restrict__ cell_start) {
    const int t = threadIdx.x;
    const int b = blockIdx.x;
    if (b < FBLOCKS) {
        int k = b * 256 + t;
        if (k < FSIZE) {
            float a  = (float)(k % FDIM - 63) * FH;
            float bb = (float)(k / FDIM - 63) * FH;
            int ixm = (__builtin_fabsf(a)  <= 5.0f) ? 0 : (a  > 0.0f ? -1 : 1);
            int iym = (__builtin_fabsf(bb) <= 5.0f) ? 0 : (bb > 0.0f ? -1 : 1);
            float s = 0.0f;
            for (int iy = -1; iy <= 1; ++iy)
                for (int ix = -1; ix <= 1; ++ix) {
                    if (ix == ixm && iy == iym) continue;
                    float xs = __builtin_fmaf(10.0f, (float)ix, a);
                    float ys = __builtin_fmaf(10.0f, (float)iy, bb);
                    s += RSQ(xs * xs + ys * ys);
                }
            float ux = 5.0f - __builtin_fabsf(__builtin_fabsf(a) - 5.0f);
            float uy = 5.0f - __builtin_fabsf(__builtin_fabsf(bb) - 5.0f);
            float r2 = __builtin_fmaf(uy, uy, ux * ux);
            float gcap = (r2 >= RC2)
                       ? RSQ(r2)
                       : __builtin_fmaf(__builtin_fmaf(GC, r2, GB), r2, GA);
            F[k] = s + gcap;
        }
    } else if (b < FBLOCKS + HISTBLOCKS) {
        __shared__ unsigned lh[NBINS];
        const int hb = b - FBLOCKS;
        for (int k = t; k < NBINS; k += 256) lh[k] = 0u;
        __syncthreads();
        const float2* p2 = (const float2*)xy;
        for (int r = 0; r < 8; ++r) {
            float2 p = p2[hb * 2048 + r * 256 + t];
            int cx = (int)(p.x * BINV); cx = cx > 63 ? 63 : cx;
            int cy = (int)(p.y * BINV); cy = cy > 63 ? 63 : cy;
            atomicAdd(&lh[cy * BGRID + cx], 1u);
        }
        __syncthreads();
        for (int k = t; k < NBINS; k += 256) hist[hb * NBINS + k] = lh[k];
    } else if (b < FBLOCKS + HISTBLOCKS + KEBLOCKS) {
        const int kb = b - FBLOCKS - HISTBLOCKS;
        const float4* p4 = (const float4*)pxy;
        float acc = 0.0f;
        for (int k = kb * 256 + t; k < (2 * N) / 4; k += KEBLOCKS * 256) {
            float4 v = p4[k];
            acc += 0.5f * (v.x * v.x + v.y * v.y + v.z * v.z + v.w * v.w);
        }
        for (int off = 32; off > 0; off >>= 1)
            acc += __shfl_down(acc, off, 64);
        __shared__ float ws[4];
        if ((t & 63) == 0) ws[t >> 6] = acc;
        __syncthreads();
        if (t == 0) ke_part[kb] = (ws[0] + ws[1]) + (ws[2] + ws[3]);
    } else {
        // ---- cell-list build (single block) ----
        __shared__ unsigned cnt[NCELLS];
        const float2* p2 = (const float2*)xy;
        for (int k = t; k < NCELLS; k += 256) cnt[k] = 0u;
        __syncthreads();
        for (int k = t; k < N; k += 256) {
            float2 p = p2[k];
            int cx = (int)(p.x * CELLINV); cx = cx > CELLG - 1 ? CELLG - 1 : cx;
            int cy = (int)(p.y * CELLINV); cy = cy > CELLG - 1 ? CELLG - 1 : cy;
            atomicAdd(&cnt[cy * CELLG + cx], 1u);
        }
        __syncthreads();
        if (t < 64) {
            unsigned carry = 0u;
            for (int ch = 0; ch < 7; ++ch) {
                int idx = ch * 64 + t;
                unsigned v = (idx < NCELLS) ? cnt[idx] : 0u;
                unsigned x = v;
                for (int off = 1; off < 64; off <<= 1) {
                    unsigned y = __shfl_up(x, off, 64);
                    if (t >= off) x += y;
                }
                unsigned excl = carry + x - v;
                if (idx < NCELLS) {
                    cell_start[idx] = (int)excl;
                    cnt[idx] = excl;
                }
                carry += __shfl(x, 63, 64);
            }
            if (t == 0) cell_start[NCELLS] = (int)carry;
        }
        __syncthreads();
        for (int k = t; k < N; k += 256) {
            float2 p = p2[k];
            int cx = (int)(p.x * CELLINV); cx = cx > CELLG - 1 ? CELLG - 1 : cx;
            int cy = (int)(p.y * CELLINV); cy = cy > CELLG - 1 ? CELLG - 1 : cy;
            unsigned slot = atomicAdd(&cnt[cy * CELLG + cx], 1u);
            sorted[slot] = p;
        }
    }
}

// main: [0,512) binned autocorr of F; [512,912) per-cell short-range (LDS-staged).
__global__ __launch_bounds__(128) void main_kernel(const float* __restrict__ F,
                                                   const unsigned* __restrict__ hist,
                                                   const float2* __restrict__ sorted,
                                                   const int* __restrict__ cell_start,
                                                   float* __restrict__ corr_part,
                                                   float* __restrict__ sr_part) {
    const int t = threadIdx.x;
    __shared__ float smem[1664];   // aliased: corr {F rows | N rows} / sr {cs|px|py|slot}
    __shared__ float wsum[2];

    if (blockIdx.x < NCORR) {
        float (*corrF)[128] = (float (*)[128])smem;           // 1024 floats
        float (*corrN)[64]  = (float (*)[64])(smem + 1024);   // 512 floats
        const int cid = blockIdx.x;
        const int y1 = cid >> 3;
        const int y2b = (cid & 7) * 8;
        const int x1 = t & 63;
        const int x2c = t >> 6;
        const int x2base = x2c * 32;
#pragma unroll
        for (int s = 0; s < 8; ++s) {
            if (t < FDIM)
                corrF[s][t] = F[(y1 - (y2b + s) + 63) * FDIM + t];
            if (t < 64) {
                int hi = (y2b + s) * BGRID + t;
                corrN[s][t] = (float)(hist[hi] + hist[NBINS + hi]
                                    + hist[2 * NBINS + hi] + hist[3 * NBINS + hi]);
            }
        }
        int h1 = y1 * BGRID + x1;
        float n1 = (float)(hist[h1] + hist[NBINS + h1]
                         + hist[2 * NBINS + h1] + hist[3 * NBINS + h1]);
        __syncthreads();
        const int fb = 63 + x1 - x2base;
        float acc = 0.0f;
#pragma unroll
        for (int s = 0; s < 8; ++s) {
            const float* Fr = &corrF[s][0];
            const float* Nr = &corrN[s][x2base];
            float sum = 0.0f;
#pragma unroll 8
            for (int k = 0; k < 32; ++k)
                sum = __builtin_fmaf(Nr[k], Fr[fb - k], sum);
            acc += sum;
        }
        acc *= n1;
        for (int off = 32; off > 0; off >>= 1)
            acc += __shfl_down(acc, off, 64);
        if ((t & 63) == 0) wsum[t >> 6] = acc;
        __syncthreads();
        if (t == 0) corr_part[cid] = wsum[0] + wsum[1];
        return;
    }

    // ---- short-range: one block per cell, neighborhood LDS-staged ----
    int*   cs    = (int*)smem;           // 401 ints
    float* spx   = smem + 512;           // 384
    float* spy   = smem + 896;           // 384
    int*   sslot = (int*)(smem + 1280);  // 384

    for (int k = t; k < NCELLS + 1; k += 128) cs[k] = cell_start[k];
    __syncthreads();

    const int c  = blockIdx.x - NCORR;   // 0..399
    const int cx = c % CELLG, cy = c / CELLG;
    const int s0 = cs[c];
    const int n0 = cs[c + 1] - s0;

    // stage 3x3 periodic neighborhood, own cell FIRST (so own points sit at [0,n0))
    const int offs[9][2] = {{0,0},{-1,-1},{0,-1},{1,-1},{-1,0},{1,0},{-1,1},{0,1},{1,1}};
    int base = 0;
#pragma unroll
    for (int nn = 0; nn < 9; ++nn) {
        int cx2 = cx + offs[nn][0];
        cx2 += (cx2 < 0) ? CELLG : 0;  cx2 -= (cx2 >= CELLG) ? CELLG : 0;
        int cy2 = cy + offs[nn][1];
        cy2 += (cy2 < 0) ? CELLG : 0;  cy2 -= (cy2 >= CELLG) ? CELLG : 0;
        int cc = cy2 * CELLG + cx2;
        int s = cs[cc], len = cs[cc + 1] - s;
        for (int k = t; k < len; k += 128) {
            int d = base + k;
            if (d < SRCAP) {
                float2 q = sorted[s + k];
                spx[d] = q.x;  spy[d] = q.y;  sslot[d] = s + k;
            }
        }
        base += len;
    }
    const int M = base > SRCAP ? SRCAP : base;
    __syncthreads();

    float acc = 0.0f;
    for (int i = 0; i < n0; ++i) {
        float pxi = spx[i], pyi = spy[i];   // uniform -> LDS broadcast
        int islot = s0 + i;
        for (int j = t; j < M; j += 128) {  // stride-1 LDS, conflict-free
            float dx = pxi - spx[j];
            float dy = pyi - spy[j];
            float ux = 5.0f - __builtin_fabsf(__builtin_fabsf(dx) - 5.0f);
            float uy = 5.0f - __builtin_fabsf(__builtin_fabsf(dy) - 5.0f);
            float s2 = __builtin_fmaf(uy, uy, ux * ux);
            float v = RSQ(s2) - __builtin_fmaf(__builtin_fmaf(GC, s2, GB), s2, GA);
            bool ok = (s2 < RC2) && (sslot[j] != islot);
            acc += ok ? v : 0.0f;
        }
    }
    for (int off = 32; off > 0; off >>= 1)
        acc += __shfl_down(acc, off, 64);
    if ((t & 63) == 0) wsum[t >> 6] = acc;
    __syncthreads();
    if (t == 0) sr_part[c] = wsum[0] + wsum[1];
}

// finish: corr + sr + KE - N*F(0) -> scalar.
__global__ __launch_bounds__(1024) void finish_kernel(const float* __restrict__ corr_part,
                                                      const float* __restrict__ sr_part,
                                                      const float* __restrict__ ke_part,
                                                      const float* __restrict__ F,
                                                      float* __restrict__ out) {
    const int t = threadIdx.x;
    float acc = 0.0f;
    if (t < NCORR) acc += corr_part[t];
    if (t < NCELLS) acc += sr_part[t];
    if (t < KEBLOCKS) acc += ke_part[t];
    if (t == 0) acc -= (float)N * F[63 * FDIM + 63];   // remove i==j bin pairs
    for (int off = 32; off > 0; off >>= 1)
        acc += __shfl_down(acc, off, 64);
    __shared__ float ws[16];
    if ((t & 63) == 0) ws[t >> 6] = acc;
    __syncthreads();
    if (t == 0) {
        float s = 0.0f;
        for (int w = 0; w < 16; ++w) s += ws[w];
        out[0] = s;
    }
}

extern "C" void kernel_launch(void* const* d_in, const int* in_sizes, int n_in,
                              void* d_out, int out_size, void* d_ws, size_t ws_size,
                              hipStream_t stream) {
    const float* xy  = (const float*)d_in[0];
    const float* pxy = (const float*)d_in[1];
    float* out       = (float*)d_out;
    float* wsf       = (float*)d_ws;
    float* F         = wsf + WS_F;
    unsigned* hist   = (unsigned*)(wsf + WS_HIST);
    float2* sorted   = (float2*)(wsf + WS_SORT);
    int* cell_start  = (int*)(wsf + WS_CSTART);
    float* corr_part = wsf + WS_CORR;
    float* sr_part   = wsf + WS_SR;
    float* ke_part   = wsf + WS_KE;

    prep_kernel<<<FBLOCKS + HISTBLOCKS + KEBLOCKS + 1, 256, 0, stream>>>(
        xy, pxy, F, hist, ke_part, sorted, cell_start);
    main_kernel<<<NCORR + NCELLS, 128, 0, stream>>>(
        F, hist, sorted, cell_start, corr_part, sr_part);
    finish_kernel<<<1, 1024, 0, stream>>>(corr_part, sr_part, ke_part, F, out);
}

// Round 20
// 32.198 us; speedup vs baseline: 1.9630x; 1.1797x over previous
//
#include <hip/hip_runtime.h>

#define N 8192

// Binned autocorrelation for the smooth part: H8 (8 non-min images) + g_cap(r_min),
// g_cap(r) = 1/r for r >= rc, C1-matched poly below rc.
#define BGRID 64
#define BINV 6.4f
#define NBINS (BGRID * BGRID)      // 4096
#define FDIM 127
#define FSIZE (FDIM * FDIM)        // 16129
#define FH 0.15625f                // 10/64

// poly(s) = GA + GB*s + GC*s^2 (s = r^2), C1-matched to 1/r at rc=0.5.
#define RC2 0.25f
#define GA 3.75f
#define GB (-10.0f)
#define GC 12.0f

// Fixed-capacity cell grid for the short-range residual (r < 0.5 only).
#define CELLG 20
#define CELLINV 2.0f
#define NCELLS (CELLG * CELLG)     // 400
#define CAP 64                     // Poisson(20.5); P(>64) ~ 1e-15
#define SRCAP 384                  // 3x3 neighborhood staging capacity (avg 185)

#define FBLOCKS 64
#define HISTBLOCKS 4
#define KEBLOCKS 8
#define BUILDBLOCKS 8
#define NCORR 512

// ws layout (float-index offsets)
#define WS_F 0                     // 16384
#define WS_HIST 16384              // 4*4096 u32 -> [16384,32768)
#define WS_CELLN 32768             // 400 u32 (pad 512)
#define WS_CELLS 33280             // 400*64 float2 = 51200 floats
#define WS_CORR 84480              // 512
#define WS_SR 84992                // 400 (pad 512)
#define WS_KE 85504                // 8

#define RSQ __builtin_amdgcn_rsqf

// prep roles: [0,64) F; [64,68) hist; [68,76) KE; [76,84) parallel cell build.
__global__ __launch_bounds__(256) void prep_kernel(const float* __restrict__ xy,
                                                   const float* __restrict__ pxy,
                                                   float* __restrict__ F,
                                                   unsigned* __restrict__ hist,
                                                   float* __restrict__ ke_part,
                                                   unsigned* __restrict__ cell_n,
                                                   float2* __restrict__ cells) {
    const int t = threadIdx.x;
    const int b = blockIdx.x;
    if (b < FBLOCKS) {
        int k = b * 256 + t;
        if (k < FSIZE) {
            float a  = (float)(k % FDIM - 63) * FH;
            float bb = (float)(k / FDIM - 63) * FH;
            int ixm = (__builtin_fabsf(a)  <= 5.0f) ? 0 : (a  > 0.0f ? -1 : 1);
            int iym = (__builtin_fabsf(bb) <= 5.0f) ? 0 : (bb > 0.0f ? -1 : 1);
            float s = 0.0f;
            for (int iy = -1; iy <= 1; ++iy)
                for (int ix = -1; ix <= 1; ++ix) {
                    if (ix == ixm && iy == iym) continue;
                    float xs = __builtin_fmaf(10.0f, (float)ix, a);
                    float ys = __builtin_fmaf(10.0f, (float)iy, bb);
                    s += RSQ(xs * xs + ys * ys);
                }
            float ux = 5.0f - __builtin_fabsf(__builtin_fabsf(a) - 5.0f);
            float uy = 5.0f - __builtin_fabsf(__builtin_fabsf(bb) - 5.0f);
            float r2 = __builtin_fmaf(uy, uy, ux * ux);
            float gcap = (r2 >= RC2)
                       ? RSQ(r2)
                       : __builtin_fmaf(__builtin_fmaf(GC, r2, GB), r2, GA);
            F[k] = s + gcap;
        }
    } else if (b < FBLOCKS + HISTBLOCKS) {
        __shared__ unsigned lh[NBINS];
        const int hb = b - FBLOCKS;
        for (int k = t; k < NBINS; k += 256) lh[k] = 0u;
        __syncthreads();
        const float2* p2 = (const float2*)xy;
        for (int r = 0; r < 8; ++r) {
            float2 p = p2[hb * 2048 + r * 256 + t];
            int cx = (int)(p.x * BINV); cx = cx > 63 ? 63 : cx;
            int cy = (int)(p.y * BINV); cy = cy > 63 ? 63 : cy;
            atomicAdd(&lh[cy * BGRID + cx], 1u);
        }
        __syncthreads();
        for (int k = t; k < NBINS; k += 256) hist[hb * NBINS + k] = lh[k];
    } else if (b < FBLOCKS + HISTBLOCKS + KEBLOCKS) {
        const int kb = b - FBLOCKS - HISTBLOCKS;
        const float4* p4 = (const float4*)pxy;
        float acc = 0.0f;
        for (int k = kb * 256 + t; k < (2 * N) / 4; k += KEBLOCKS * 256) {
            float4 v = p4[k];
            acc += 0.5f * (v.x * v.x + v.y * v.y + v.z * v.z + v.w * v.w);
        }
        for (int off = 32; off > 0; off >>= 1)
            acc += __shfl_down(acc, off, 64);
        __shared__ float ws[4];
        if ((t & 63) == 0) ws[t >> 6] = acc;
        __syncthreads();
        if (t == 0) ke_part[kb] = (ws[0] + ws[1]) + (ws[2] + ws[3]);
    } else {
        // parallel cell build: 8 blocks x 1024 points, global-atomic slot assign
        const int pb = b - FBLOCKS - HISTBLOCKS - KEBLOCKS;
        const float2* p2 = (const float2*)xy;
        for (int k = pb * 1024 + t; k < pb * 1024 + 1024; k += 256) {
            float2 p = p2[k];
            int cx = (int)(p.x * CELLINV); cx = cx > CELLG - 1 ? CELLG - 1 : cx;
            int cy = (int)(p.y * CELLINV); cy = cy > CELLG - 1 ? CELLG - 1 : cy;
            int c = cy * CELLG + cx;
            unsigned slot = atomicAdd(&cell_n[c], 1u);
            if (slot < CAP) cells[c * CAP + slot] = p;
        }
    }
}

// main: [0,512) binned autocorr of F; [512,912) per-cell short-range residual.
__global__ __launch_bounds__(128) void main_kernel(const float* __restrict__ F,
                                                   const unsigned* __restrict__ hist,
                                                   const unsigned* __restrict__ cell_n,
                                                   const float2* __restrict__ cells,
                                                   float* __restrict__ corr_part,
                                                   float* __restrict__ sr_part) {
    const int t = threadIdx.x;
    __shared__ float smem[1664];   // aliased between the two roles
    __shared__ float wsum[2];

    if (blockIdx.x < NCORR) {
        float (*corrF)[128] = (float (*)[128])smem;           // 1024
        float (*corrN)[64]  = (float (*)[64])(smem + 1024);   // 512
        const int cid = blockIdx.x;
        const int y1 = cid >> 3;
        const int y2b = (cid & 7) * 8;
        const int x1 = t & 63;
        const int x2c = t >> 6;
        const int x2base = x2c * 32;
#pragma unroll
        for (int s = 0; s < 8; ++s) {
            if (t < FDIM)
                corrF[s][t] = F[(y1 - (y2b + s) + 63) * FDIM + t];
            if (t < 64) {
                int hi = (y2b + s) * BGRID + t;
                corrN[s][t] = (float)(hist[hi] + hist[NBINS + hi]
                                    + hist[2 * NBINS + hi] + hist[3 * NBINS + hi]);
            }
        }
        int h1 = y1 * BGRID + x1;
        float n1 = (float)(hist[h1] + hist[NBINS + h1]
                         + hist[2 * NBINS + h1] + hist[3 * NBINS + h1]);
        __syncthreads();
        const int fb = 63 + x1 - x2base;
        float acc = 0.0f;
#pragma unroll
        for (int s = 0; s < 8; ++s) {
            const float* Fr = &corrF[s][0];
            const float* Nr = &corrN[s][x2base];
            float sum = 0.0f;
#pragma unroll 8
            for (int k = 0; k < 32; ++k)
                sum = __builtin_fmaf(Nr[k], Fr[fb - k], sum);
            acc += sum;
        }
        acc *= n1;
        for (int off = 32; off > 0; off >>= 1)
            acc += __shfl_down(acc, off, 64);
        if ((t & 63) == 0) wsum[t >> 6] = acc;
        __syncthreads();
        if (t == 0) corr_part[cid] = wsum[0] + wsum[1];
        return;
    }

    // ---- short-range: one block per cell, 3x3 neighborhood LDS-staged ----
    float* spx  = smem;                  // 384
    float* spy  = smem + 384;            // 384
    int*   stag = (int*)(smem + 768);    // 384

    const int c  = blockIdx.x - NCORR;   // 0..399
    const int cx = c % CELLG, cy = c / CELLG;

    const int offs[9][2] = {{0,0},{-1,-1},{0,-1},{1,-1},{-1,0},{1,0},{-1,1},{0,1},{1,1}};
    int base = 0, n0 = 0;
#pragma unroll
    for (int nn = 0; nn < 9; ++nn) {
        int cx2 = cx + offs[nn][0];
        cx2 += (cx2 < 0) ? CELLG : 0;  cx2 -= (cx2 >= CELLG) ? CELLG : 0;
        int cy2 = cy + offs[nn][1];
        cy2 += (cy2 < 0) ? CELLG : 0;  cy2 -= (cy2 >= CELLG) ? CELLG : 0;
        int cc = cy2 * CELLG + cx2;
        int len = (int)cell_n[cc];  len = len > CAP ? CAP : len;
        if (nn == 0) n0 = len;       // own cell staged first -> [0, n0)
        for (int k = t; k < len; k += 128) {
            int d = base + k;
            if (d < SRCAP) {
                float2 q = cells[cc * CAP + k];
                spx[d] = q.x;  spy[d] = q.y;  stag[d] = cc * CAP + k;
            }
        }
        base += len;
    }
    const int M = base > SRCAP ? SRCAP : base;
    __syncthreads();

    float acc = 0.0f;
    for (int i = 0; i < n0; ++i) {
        float pxi = spx[i], pyi = spy[i];     // uniform -> LDS broadcast
        int itag = c * CAP + i;
        for (int j = t; j < M; j += 128) {    // stride-1 LDS
            float dx = pxi - spx[j];
            float dy = pyi - spy[j];
            float ux = 5.0f - __builtin_fabsf(__builtin_fabsf(dx) - 5.0f);
            float uy = 5.0f - __builtin_fabsf(__builtin_fabsf(dy) - 5.0f);
            float s2 = __builtin_fmaf(uy, uy, ux * ux);
            float v = RSQ(s2) - __builtin_fmaf(__builtin_fmaf(GC, s2, GB), s2, GA);
            bool ok = (s2 < RC2) && (stag[j] != itag);
            acc += ok ? v : 0.0f;
        }
    }
    for (int off = 32; off > 0; off >>= 1)
        acc += __shfl_down(acc, off, 64);
    if ((t & 63) == 0) wsum[t >> 6] = acc;
    __syncthreads();
    if (t == 0) sr_part[c] = wsum[0] + wsum[1];
}

// finish: corr + sr + KE - N*F(0) -> scalar.
__global__ __launch_bounds__(1024) void finish_kernel(const float* __restrict__ corr_part,
                                                      const float* __restrict__ sr_part,
                                                      const float* __restrict__ ke_part,
                                                      const float* __restrict__ F,
                                                      float* __restrict__ out) {
    const int t = threadIdx.x;
    float acc = 0.0f;
    if (t < NCORR) acc += corr_part[t];
    if (t < NCELLS) acc += sr_part[t];
    if (t < KEBLOCKS) acc += ke_part[t];
    if (t == 0) acc -= (float)N * F[63 * FDIM + 63];   // remove i==j bin pairs
    for (int off = 32; off > 0; off >>= 1)
        acc += __shfl_down(acc, off, 64);
    __shared__ float ws[16];
    if ((t & 63) == 0) ws[t >> 6] = acc;
    __syncthreads();
    if (t == 0) {
        float s = 0.0f;
        for (int w = 0; w < 16; ++w) s += ws[w];
        out[0] = s;
    }
}

extern "C" void kernel_launch(void* const* d_in, const int* in_sizes, int n_in,
                              void* d_out, int out_size, void* d_ws, size_t ws_size,
                              hipStream_t stream) {
    const float* xy  = (const float*)d_in[0];
    const float* pxy = (const float*)d_in[1];
    float* out       = (float*)d_out;
    float* wsf       = (float*)d_ws;
    float* F         = wsf + WS_F;
    unsigned* hist   = (unsigned*)(wsf + WS_HIST);
    unsigned* cell_n = (unsigned*)(wsf + WS_CELLN);
    float2* cells    = (float2*)(wsf + WS_CELLS);
    float* corr_part = wsf + WS_CORR;
    float* sr_part   = wsf + WS_SR;
    float* ke_part   = wsf + WS_KE;

    hipMemsetAsync(cell_n, 0, NCELLS * sizeof(unsigned), stream);
    prep_kernel<<<FBLOCKS + HISTBLOCKS + KEBLOCKS + BUILDBLOCKS, 256, 0, stream>>>(
        xy, pxy, F, hist, ke_part, cell_n, cells);
    main_kernel<<<NCORR + NCELLS, 128, 0, stream>>>(
        F, hist, cell_n, cells, corr_part, sr_part);
    finish_kernel<<<1, 1024, 0, stream>>>(corr_part, sr_part, ke_part, F, out);
}

// Round 21
// 27.395 us; speedup vs baseline: 2.3072x; 1.1753x over previous
//
#include <hip/hip_runtime.h>

#define N 8192

// Binned autocorrelation for the smooth part: H8 (8 non-min images) + g_cap(r_min),
// g_cap(r) = 1/r for r >= rc, C1-matched poly below rc.
#define BGRID 64
#define BINV 6.4f
#define NBINS (BGRID * BGRID)      // 4096
#define FDIM 127
#define FSIZE (FDIM * FDIM)        // 16129
#define FH 0.15625f                // 10/64

// poly(s) = GA + GB*s + GC*s^2 (s = r^2), C1-matched to 1/r at rc=0.5.
#define RC2 0.25f
#define GA 3.75f
#define GB (-10.0f)
#define GC 12.0f

// Per-slice privatized cell grid: 8 slices x 400 cells x 24 slots.
#define CELLG 20
#define CELLINV 2.0f
#define NCELLS (CELLG * CELLG)     // 400
#define NSLICE 8
#define CAPS 24                    // Poisson(2.56) per slice-cell; P(>24) ~ 1e-14
#define SRCAP 384                  // 3x3 neighborhood staging capacity (avg 185)

#define FBLOCKS 64
#define HISTBLOCKS 4
#define KEBLOCKS 8
#define NCORR 512

// ws layout (float-index offsets)
#define WS_F 0                     // 16384
#define WS_HIST 16384              // 4*4096 u32 -> [16384,32768)
#define WS_CNT 32768               // 400*8 u32 (pad 4096) -> [32768,36864)
#define WS_CELLS 36864             // 400*8*24 float2 = 153600 floats
#define WS_CORR 190464             // 512
#define WS_SR 190976               // 512
#define WS_KE 191488               // 8

#define RSQ __builtin_amdgcn_rsqf

// prep roles: [0,64) F; [64,68) hist; [68,76) KE; [76,84) per-slice cell build.
__global__ __launch_bounds__(256) void prep_kernel(const float* __restrict__ xy,
                                                   const float* __restrict__ pxy,
                                                   float* __restrict__ F,
                                                   unsigned* __restrict__ hist,
                                                   float* __restrict__ ke_part,
                                                   unsigned* __restrict__ cnt_g,
                                                   float2* __restrict__ cells) {
    const int t = threadIdx.x;
    const int b = blockIdx.x;
    if (b < FBLOCKS) {
        int k = b * 256 + t;
        if (k < FSIZE) {
            float a  = (float)(k % FDIM - 63) * FH;
            float bb = (float)(k / FDIM - 63) * FH;
            int ixm = (__builtin_fabsf(a)  <= 5.0f) ? 0 : (a  > 0.0f ? -1 : 1);
            int iym = (__builtin_fabsf(bb) <= 5.0f) ? 0 : (bb > 0.0f ? -1 : 1);
            float s = 0.0f;
            for (int iy = -1; iy <= 1; ++iy)
                for (int ix = -1; ix <= 1; ++ix) {
                    if (ix == ixm && iy == iym) continue;
                    float xs = __builtin_fmaf(10.0f, (float)ix, a);
                    float ys = __builtin_fmaf(10.0f, (float)iy, bb);
                    s += RSQ(xs * xs + ys * ys);
                }
            float ux = 5.0f - __builtin_fabsf(__builtin_fabsf(a) - 5.0f);
            float uy = 5.0f - __builtin_fabsf(__builtin_fabsf(bb) - 5.0f);
            float r2 = __builtin_fmaf(uy, uy, ux * ux);
            float gcap = (r2 >= RC2)
                       ? RSQ(r2)
                       : __builtin_fmaf(__builtin_fmaf(GC, r2, GB), r2, GA);
            F[k] = s + gcap;
        }
    } else if (b < FBLOCKS + HISTBLOCKS) {
        __shared__ unsigned lh[NBINS];
        const int hb = b - FBLOCKS;
        for (int k = t; k < NBINS; k += 256) lh[k] = 0u;
        __syncthreads();
        const float2* p2 = (const float2*)xy;
        for (int r = 0; r < 8; ++r) {
            float2 p = p2[hb * 2048 + r * 256 + t];
            int cx = (int)(p.x * BINV); cx = cx > 63 ? 63 : cx;
            int cy = (int)(p.y * BINV); cy = cy > 63 ? 63 : cy;
            atomicAdd(&lh[cy * BGRID + cx], 1u);
        }
        __syncthreads();
        for (int k = t; k < NBINS; k += 256) hist[hb * NBINS + k] = lh[k];
    } else if (b < FBLOCKS + HISTBLOCKS + KEBLOCKS) {
        const int kb = b - FBLOCKS - HISTBLOCKS;
        const float4* p4 = (const float4*)pxy;
        float acc = 0.0f;
        for (int k = kb * 256 + t; k < (2 * N) / 4; k += KEBLOCKS * 256) {
            float4 v = p4[k];
            acc += 0.5f * (v.x * v.x + v.y * v.y + v.z * v.z + v.w * v.w);
        }
        for (int off = 32; off > 0; off >>= 1)
            acc += __shfl_down(acc, off, 64);
        __shared__ float ws[4];
        if ((t & 63) == 0) ws[t >> 6] = acc;
        __syncthreads();
        if (t == 0) ke_part[kb] = (ws[0] + ws[1]) + (ws[2] + ws[3]);
    } else {
        // per-slice cell build: LDS cursors only, plain global stores, no memset
        __shared__ unsigned cur[NCELLS];
        const int pb = b - FBLOCKS - HISTBLOCKS - KEBLOCKS;   // slice 0..7
        const float2* p2 = (const float2*)xy;
        for (int k = t; k < NCELLS; k += 256) cur[k] = 0u;
        __syncthreads();
        for (int r = 0; r < 4; ++r) {
            float2 p = p2[pb * 1024 + r * 256 + t];
            int cx = (int)(p.x * CELLINV); cx = cx > CELLG - 1 ? CELLG - 1 : cx;
            int cy = (int)(p.y * CELLINV); cy = cy > CELLG - 1 ? CELLG - 1 : cy;
            int c = cy * CELLG + cx;
            unsigned slot = atomicAdd(&cur[c], 1u);
            if (slot < CAPS) cells[(c * NSLICE + pb) * CAPS + slot] = p;
        }
        __syncthreads();
        for (int k = t; k < NCELLS; k += 256) cnt_g[k * NSLICE + pb] = cur[k];
    }
}

// main: [0,512) binned autocorr of F; [512,912) per-cell short-range residual.
__global__ __launch_bounds__(128) void main_kernel(const float* __restrict__ F,
                                                   const unsigned* __restrict__ hist,
                                                   const unsigned* __restrict__ cnt_g,
                                                   const float2* __restrict__ cells,
                                                   float* __restrict__ corr_part,
                                                   float* __restrict__ sr_part) {
    const int t = threadIdx.x;
    __shared__ float smem[1664];   // aliased between the two roles
    __shared__ float wsum[2];

    if (blockIdx.x < NCORR) {
        float (*corrF)[128] = (float (*)[128])smem;           // 1024
        float (*corrN)[64]  = (float (*)[64])(smem + 1024);   // 512
        const int cid = blockIdx.x;
        const int y1 = cid >> 3;
        const int y2b = (cid & 7) * 8;
        const int x1 = t & 63;
        const int x2c = t >> 6;
        const int x2base = x2c * 32;
#pragma unroll
        for (int s = 0; s < 8; ++s) {
            if (t < FDIM)
                corrF[s][t] = F[(y1 - (y2b + s) + 63) * FDIM + t];
            if (t < 64) {
                int hi = (y2b + s) * BGRID + t;
                corrN[s][t] = (float)(hist[hi] + hist[NBINS + hi]
                                    + hist[2 * NBINS + hi] + hist[3 * NBINS + hi]);
            }
        }
        int h1 = y1 * BGRID + x1;
        float n1 = (float)(hist[h1] + hist[NBINS + h1]
                         + hist[2 * NBINS + h1] + hist[3 * NBINS + h1]);
        __syncthreads();
        const int fb = 63 + x1 - x2base;
        float acc = 0.0f;
#pragma unroll
        for (int s = 0; s < 8; ++s) {
            const float* Fr = &corrF[s][0];
            const float* Nr = &corrN[s][x2base];
            float sum = 0.0f;
#pragma unroll 8
            for (int k = 0; k < 32; ++k)
                sum = __builtin_fmaf(Nr[k], Fr[fb - k], sum);
            acc += sum;
        }
        acc *= n1;
        for (int off = 32; off > 0; off >>= 1)
            acc += __shfl_down(acc, off, 64);
        if ((t & 63) == 0) wsum[t >> 6] = acc;
        __syncthreads();
        if (t == 0) corr_part[cid] = wsum[0] + wsum[1];
        return;
    }

    // ---- short-range: one block per cell, 72-segment flattened LDS staging ----
    float* spx      = smem;                    // 384
    float* spy      = smem + 384;              // 384
    int*   stag     = (int*)(smem + 768);      // 384
    int*   segbase  = (int*)(smem + 1152);     // 73
    unsigned* seglen = (unsigned*)(smem + 1225); // 72
    int*   cc9      = (int*)(smem + 1297);     // 9

    const int c  = blockIdx.x - NCORR;         // 0..399
    const int cx = c % CELLG, cy = c / CELLG;

    if (t < 9) {
        const int ox[9] = {0,-1,0,1,-1,1,-1,0,1};
        const int oy[9] = {0,-1,-1,-1,0,0,1,1,1};   // own cell first
        int cx2 = cx + ox[t];
        cx2 += (cx2 < 0) ? CELLG : 0;  cx2 -= (cx2 >= CELLG) ? CELLG : 0;
        int cy2 = cy + oy[t];
        cy2 += (cy2 < 0) ? CELLG : 0;  cy2 -= (cy2 >= CELLG) ? CELLG : 0;
        cc9[t] = cy2 * CELLG + cx2;
    }
    __syncthreads();
    if (t < 72) {
        unsigned L = cnt_g[cc9[t >> 3] * NSLICE + (t & 7)];
        seglen[t] = L > CAPS ? CAPS : L;
    }
    __syncthreads();
    if (t < 73) {               // parallel prefix (72 LDS reads max, all threads concurrent)
        int b2 = 0;
        for (int j = 0; j < t; ++j) b2 += (int)seglen[j];
        segbase[t] = b2;
    }
    __syncthreads();
    const int n0 = segbase[8];                     // own-cell points staged at [0,n0)
    int M = segbase[72];  M = M > SRCAP ? SRCAP : M;

    for (int g = t; g < M; g += 128) {
        int lo = 0, hi = 71;
        while (lo < hi) {                          // 7-step binary search
            int mid = (lo + hi + 1) >> 1;
            if (segbase[mid] <= g) lo = mid; else hi = mid - 1;
        }
        int src = (cc9[lo >> 3] * NSLICE + (lo & 7)) * CAPS + (g - segbase[lo]);
        float2 q = cells[src];
        spx[g] = q.x;  spy[g] = q.y;  stag[g] = src;
    }
    __syncthreads();

    float acc = 0.0f;
    for (int i = 0; i < n0; ++i) {
        float pxi = spx[i], pyi = spy[i];          // uniform -> LDS broadcast
        int itag = stag[i];
        for (int j = t; j < M; j += 128) {         // stride-1 LDS
            float dx = pxi - spx[j];
            float dy = pyi - spy[j];
            float ux = 5.0f - __builtin_fabsf(__builtin_fabsf(dx) - 5.0f);
            float uy = 5.0f - __builtin_fabsf(__builtin_fabsf(dy) - 5.0f);
            float s2 = __builtin_fmaf(uy, uy, ux * ux);
            float v = RSQ(s2) - __builtin_fmaf(__builtin_fmaf(GC, s2, GB), s2, GA);
            bool ok = (s2 < RC2) && (stag[j] != itag);
            acc += ok ? v : 0.0f;
        }
    }
    for (int off = 32; off > 0; off >>= 1)
        acc += __shfl_down(acc, off, 64);
    if ((t & 63) == 0) wsum[t >> 6] = acc;
    __syncthreads();
    if (t == 0) sr_part[c] = wsum[0] + wsum[1];
}

// finish: corr + sr + KE - N*F(0) -> scalar.
__global__ __launch_bounds__(1024) void finish_kernel(const float* __restrict__ corr_part,
                                                      const float* __restrict__ sr_part,
                                                      const float* __restrict__ ke_part,
                                                      const float* __restrict__ F,
                                                      float* __restrict__ out) {
    const int t = threadIdx.x;
    float acc = 0.0f;
    if (t < NCORR) acc += corr_part[t];
    if (t < NCELLS) acc += sr_part[t];
    if (t < KEBLOCKS) acc += ke_part[t];
    if (t == 0) acc -= (float)N * F[63 * FDIM + 63];   // remove i==j bin pairs
    for (int off = 32; off > 0; off >>= 1)
        acc += __shfl_down(acc, off, 64);
    __shared__ float ws[16];
    if ((t & 63) == 0) ws[t >> 6] = acc;
    __syncthreads();
    if (t == 0) {
        float s = 0.0f;
        for (int w = 0; w < 16; ++w) s += ws[w];
        out[0] = s;
    }
}

extern "C" void kernel_launch(void* const* d_in, const int* in_sizes, int n_in,
                              void* d_out, int out_size, void* d_ws, size_t ws_size,
                              hipStream_t stream) {
    const float* xy  = (const float*)d_in[0];
    const float* pxy = (const float*)d_in[1];
    float* out       = (float*)d_out;
    float* wsf       = (float*)d_ws;
    float* F         = wsf + WS_F;
    unsigned* hist   = (unsigned*)(wsf + WS_HIST);
    unsigned* cnt_g  = (unsigned*)(wsf + WS_CNT);
    float2* cells    = (float2*)(wsf + WS_CELLS);
    float* corr_part = wsf + WS_CORR;
    float* sr_part   = wsf + WS_SR;
    float* ke_part   = wsf + WS_KE;

    prep_kernel<<<FBLOCKS + HISTBLOCKS + KEBLOCKS + NSLICE, 256, 0, stream>>>(
        xy, pxy, F, hist, ke_part, cnt_g, cells);
    main_kernel<<<NCORR + NCELLS, 128, 0, stream>>>(
        F, hist, cnt_g, cells, corr_part, sr_part);
    finish_kernel<<<1, 1024, 0, stream>>>(corr_part, sr_part, ke_part, F, out);
}